// Round 11
// baseline (124.521 us; speedup 1.0000x reference)
//
#include <hip/hip_runtime.h>
#include <hip/hip_bf16.h>
#include <hip/hip_fp16.h>

// Problem: B=8192, T=128, D=7, I=128, C=10, H=64, L=128
// ws layout (float slots):
//   sPack fp16 [128][8192][8]  off 0          (4,194,304)  d0..6 = s, d7 = junk
//   attnB fp16 [8192][128]     off 4,194,304  (524,288)
//   LPb   fp16 B-frags         off 4,718,592  (262,144)
//   partial [16][8192][10]     off 4,980,736  (1,310,720)
// total 6,291,456 floats = 25.2 MB

#define BB 8192
#define TT 128
#define II 128
#define CC 10
#define HH 64

#define OFF_SP  0
#define OFF_AT  4194304
#define OFF_LPB 4718592
#define OFF_PT  4980736

typedef __attribute__((ext_vector_type(8))) short short8;
typedef __attribute__((ext_vector_type(16))) float floatx16;

static __device__ inline unsigned int pkbf(float lo, float hi) {
  __hip_bfloat162 h = __float22bfloat162_rn(make_float2(lo, hi));
  unsigned int u;
  __builtin_memcpy(&u, &h, 4);
  return u;
}

static __device__ inline unsigned int pkh(float lo, float hi) {
  __half2 h = __float22half2_rn(make_float2(lo, hi));
  unsigned int u;
  __builtin_memcpy(&u, &h, 4);
  return u;
}

static __device__ inline short8 cvt8(float4 a, float4 b) {
  union { short8 v; unsigned int u[4]; } r;
  r.u[0] = pkbf(a.x, a.y);
  r.u[1] = pkbf(a.z, a.w);
  r.u[2] = pkbf(b.x, b.y);
  r.u[3] = pkbf(b.z, b.w);
  return r.v;
}

// ---------------- Kernel 1: zs via MFMA -> sPack directly (LDS transpose) ----
// grid (32 ns x 32 mb); block 256 = 4 waves. Tile = rows m0..m0+31 where
// m0 = mb*28 -> trees 4mb..4mb+3 are COMPLETE within the tile (28 rows used,
// 4-row overlap waste). s-values transposed through 16KB LDS, stored as one
// coalesced uint4 per (t,b). No attn-branch LDS/reg envelope -> (256,4),
// ~8 blocks/CU (R10's fused phase1 sat at <=4 blocks/CU because attn's
// 34.8KB LDS was reserved for all 1024 blocks).
__global__ __launch_bounds__(256, 4) void zs_kernel(
    const float* __restrict__ mask, const float* __restrict__ x,
    const float* __restrict__ thr, __half* __restrict__ sPack) {
  __shared__ __half lds[4 * 256 * 8];   // 16 KB: [tree_local][b_local][8]
  const int ns = blockIdx.x;            // 0..31, 256 b each
  const int mb = blockIdx.y;            // 0..31, rows mb*28 .. +31
  const int tid = threadIdx.x;
  const int wv = tid >> 6, lane = tid & 63;
  const int half = lane >> 5, l31 = lane & 31;
  const int m0 = mb * 28;

  // A-frags from mask rows m0+l31 (clamp OOB rows; results discarded)
  int mr = m0 + l31; if (mr > 895) mr = 895;
  const float* mrow = mask + (size_t)mr * II + half * 8;
  short8 af[8];
#pragma unroll
  for (int s = 0; s < 8; ++s)
    af[s] = cvt8(*(const float4*)(mrow + s * 16),
                 *(const float4*)(mrow + s * 16 + 4));
  float th[16];
#pragma unroll
  for (int r = 0; r < 16; ++r) {
    int m = m0 + (r & 3) + 8 * (r >> 2) + 4 * half;
    th[r] = thr[m > 895 ? 895 : m];
  }

#pragma unroll
  for (int nb = 0; nb < 2; ++nb) {
    const int nl = wv * 64 + nb * 32;        // b_local of this 32-tile
    const float* xrow = x + (size_t)(ns * 256 + nl + l31) * II + half * 8;
    floatx16 acc;
#pragma unroll
    for (int i = 0; i < 16; ++i) acc[i] = 0.f;
#pragma unroll
    for (int s = 0; s < 8; ++s) {
      short8 bf = cvt8(*(const float4*)(xrow + s * 16),
                       *(const float4*)(xrow + s * 16 + 4));
      acc = __builtin_amdgcn_mfma_f32_32x32x16_bf16(af[s], bf, acc, 0, 0, 0);
    }
#pragma unroll
    for (int r = 0; r < 16; ++r) {
      int row = (r & 3) + 8 * (r >> 2) + 4 * half;   // 0..31
      if (row < 28) {
        int tl = row / 7;                  // tree_local 0..3 (m0 = 28*mb)
        int d = row - tl * 7;
        float z = acc[r] - th[r];
        float o = 0.5f * (z / (1.f + fabsf(z)) + 1.f);
        lds[(tl * 256 + nl + l31) * 8 + d] = __float2half(o);
      }
    }
  }
  __syncthreads();

  // coalesced store: 4 uint4/thread; slot 7 is junk (never read by main)
  const uint4* l4 = (const uint4*)lds;
#pragma unroll
  for (int j = 0; j < 4; ++j) {
    int idx = tid + 256 * j;               // tree = idx>>8, bl = idx&255
    ((uint4*)sPack)[(size_t)(4 * mb + (idx >> 8)) * BB + ns * 256 + (idx & 255)] =
        l4[idx];
  }
}

// ---------------- Kernel 2: attn (MFMA) + prep ------------------------------
// blocks [0,64): attn | [64,128): prep. Heavy reg/LDS envelope isolated here
// (only 128 blocks). (256,2): attn holds ~160+ unified regs (R7: (256,4)
// spilled, +18us).
__global__ __launch_bounds__(256, 2) void attn_prep_kernel(
    const float* __restrict__ x, const float* __restrict__ lo,
    const float* __restrict__ W1, const float* __restrict__ b1,
    const float* __restrict__ W2, const float* __restrict__ b2,
    __half* __restrict__ attnB, unsigned int* __restrict__ lpb) {
  __shared__ float smem[8704];   // 34.8 KB
  const int blk = blockIdx.x;
  const int tid = threadIdx.x;
  const int wv = tid >> 6, lane = tid & 63;
  const int half = lane >> 5, l31 = lane & 31;

  if (blk < 64) {
    // ---------------- attn branch: 128 b-rows/block, 32/wave ----------------
    const int b0 = blk * 128 + wv * 32;

    short8 axf[8];
    const float* xrow = x + (size_t)(b0 + l31) * II + half * 8;
#pragma unroll
    for (int s = 0; s < 8; ++s)
      axf[s] = cvt8(*(const float4*)(xrow + s * 16),
                    *(const float4*)(xrow + s * 16 + 4));

    floatx16 acch[2];
#pragma unroll
    for (int i = 0; i < 16; ++i) { acch[0][i] = 0.f; acch[1][i] = 0.f; }
#pragma unroll
    for (int s = 0; s < 8; ++s) {
#pragma unroll
      for (int tile = 0; tile < 2; ++tile) {
        union { short8 v; unsigned int u[4]; } wf;
#pragma unroll
        for (int jp = 0; jp < 4; ++jp) {
          int k0 = s * 16 + half * 8 + jp * 2;
          float f0 = W1[(size_t)k0 * HH + tile * 32 + l31];
          float f1 = W1[(size_t)(k0 + 1) * HH + tile * 32 + l31];
          wf.u[jp] = pkbf(f0, f1);
        }
        acch[tile] = __builtin_amdgcn_mfma_f32_32x32x16_bf16(
            axf[s], wf.v, acch[tile], 0, 0, 0);
      }
    }
    float* hids = smem + wv * 2176;
#pragma unroll
    for (int tile = 0; tile < 2; ++tile) {
      float bh = b1[tile * 32 + l31];
#pragma unroll
      for (int r = 0; r < 16; ++r) {
        int row = (r & 3) + 8 * (r >> 2) + 4 * half;
        hids[row * 68 + tile * 32 + l31] = fmaxf(acch[tile][r] + bh, 0.f);
      }
    }
    __syncthreads();

    short8 ahf[4];
#pragma unroll
    for (int s = 0; s < 4; ++s) {
      const float* hr = hids + l31 * 68 + s * 16 + half * 8;
      ahf[s] = cvt8(*(const float4*)hr, *(const float4*)(hr + 4));
    }

    floatx16 accl[4];
#pragma unroll
    for (int tile = 0; tile < 4; ++tile) {
#pragma unroll
      for (int i = 0; i < 16; ++i) accl[tile][i] = 0.f;
#pragma unroll
      for (int s = 0; s < 4; ++s) {
        union { short8 v; unsigned int u[4]; } wf;
#pragma unroll
        for (int jp = 0; jp < 4; ++jp) {
          int k0 = s * 16 + half * 8 + jp * 2;
          float f0 = W2[(size_t)k0 * TT + tile * 32 + l31];
          float f1 = W2[(size_t)(k0 + 1) * TT + tile * 32 + l31];
          wf.u[jp] = pkbf(f0, f1);
        }
        accl[tile] = __builtin_amdgcn_mfma_f32_32x32x16_bf16(
            ahf[s], wf.v, accl[tile], 0, 0, 0);
      }
      float bt = b2[tile * 32 + l31];
#pragma unroll
      for (int i = 0; i < 16; ++i) accl[tile][i] += bt;
    }

    // softmax over t, butterfly reduce
    float mrow[16];
#pragma unroll
    for (int r = 0; r < 16; ++r)
      mrow[r] = fmaxf(fmaxf(accl[0][r], accl[1][r]),
                      fmaxf(accl[2][r], accl[3][r]));
#pragma unroll
    for (int msk = 1; msk <= 16; msk <<= 1)
#pragma unroll
      for (int r = 0; r < 16; ++r)
        mrow[r] = fmaxf(mrow[r], __shfl_xor(mrow[r], msk, 64));
    float srow[16];
#pragma unroll
    for (int r = 0; r < 16; ++r) srow[r] = 0.f;
#pragma unroll
    for (int tile = 0; tile < 4; ++tile)
#pragma unroll
      for (int r = 0; r < 16; ++r) {
        float e = __expf(accl[tile][r] - mrow[r]);
        accl[tile][r] = e;
        srow[r] += e;
      }
#pragma unroll
    for (int msk = 1; msk <= 16; msk <<= 1)
#pragma unroll
      for (int r = 0; r < 16; ++r)
        srow[r] += __shfl_xor(srow[r], msk, 64);
#pragma unroll
    for (int r = 0; r < 16; ++r) srow[r] = 1.f / srow[r];

#pragma unroll
    for (int tile = 0; tile < 4; ++tile)
#pragma unroll
      for (int r = 0; r < 16; ++r) {
        int row = (r & 3) + 8 * (r >> 2) + 4 * half;
        attnB[(size_t)(b0 + row) * TT + tile * 32 + l31] =
            __float2half(accl[tile][r] * srow[r]);
      }

  } else {
    // ---------------- prep branch: leaf softmax -> fp16 B-frags -------------
    float* lps = smem;   // 3072 floats
    const int t0 = (blk - 64) * 2;
    {
      int tl = tid >> 7, l = tid & 127;
      const float* row = lo + ((size_t)(t0 + tl) * 128 + l) * CC;
      float v[CC];
      float m = -1e30f;
#pragma unroll
      for (int c = 0; c < CC; ++c) { v[c] = row[c]; m = fmaxf(m, v[c]); }
      float s = 0.f;
#pragma unroll
      for (int c = 0; c < CC; ++c) { v[c] = __expf(v[c] - m); s += v[c]; }
      float inv = 1.f / s;
      float* o = lps + (tl * 128 + l) * 12;
#pragma unroll
      for (int c = 0; c < CC; ++c) o[c] = v[c] * inv;
      o[10] = 0.f; o[11] = 0.f;
    }
    __syncthreads();

#pragma unroll
    for (int jj = 0; jj < 4; ++jj) {
      int idx = tid + 256 * jj;           // 0..1023 = (tl, s, lane)
      int tl = idx >> 9, rem = idx & 511;
      int s = rem >> 6, ln = rem & 63;
      int hf = ln >> 5, n = ln & 31;
      unsigned int wd[4];
#pragma unroll
      for (int jp = 0; jp < 4; ++jp) {
        int l0 = s * 16 + hf * 8 + jp * 2;
        float f0 = (n < CC) ? lps[(tl * 128 + l0) * 12 + n] : 0.f;
        float f1 = (n < CC) ? lps[(tl * 128 + l0 + 1) * 12 + n] : 0.f;
        wd[jp] = pkh(f0, f1);
      }
      ((uint4*)lpb)[(size_t)(t0 + tl) * 512 + s * 64 + ln] =
          make_uint4(wd[0], wd[1], wd[2], wd[3]);
    }
  }
}

// ---------------- Kernel 3: main contraction via MFMA (fp16) ----------------
// grid (64 bg of 128 b, 16 tg of 8 trees); block 256 = 4 waves.
__global__ __launch_bounds__(256, 4) void main_kernel(
    const __half* __restrict__ sPack, const __half* __restrict__ attnB,
    const unsigned int* __restrict__ lpb, float* __restrict__ partial) {
  __shared__ float red[128 * 10];
  const int bg = blockIdx.x, tg = blockIdx.y;
  const int tid = threadIdx.x;
  const int w = tid >> 6, lane = tid & 63;
  const int half = lane >> 5;
  const int b = bg * 128 + w * 32 + (lane & 31);
  const uint4* spk = (const uint4*)sPack;

  __half av[8];
  *(uint4*)av = *(const uint4*)(attnB + (size_t)b * TT + tg * 8);

  floatx16 acc;
#pragma unroll
  for (int i = 0; i < 16; ++i) acc[i] = 0.f;

  uint4 sv[2];
  sv[0] = spk[(size_t)(tg * 8) * BB + b];

#pragma unroll
  for (int it = 0; it < 8; ++it) {
    const int cur = it & 1;
    const int t = tg * 8 + it;
    uint4 bf[8];
    const uint4* lpt = (const uint4*)lpb + (size_t)t * 512 + lane;
#pragma unroll
    for (int s = 0; s < 8; ++s) bf[s] = lpt[s * 64];
    if (it < 7) sv[cur ^ 1] = spk[(size_t)(t + 1) * BB + b];

    const __half* sh = (const __half*)&sv[cur];
    float s0 = __half2float(sh[0]), s1 = __half2float(sh[1]);
    float s2 = __half2float(sh[2]), s3 = __half2float(sh[3]);
    float s4 = __half2float(sh[4]), s5 = __half2float(sh[5]);
    float s6 = __half2float(sh[6]);
    float A  = __half2float(av[it]);

    float s0c = 1.f - s0, s1c = 1.f - s1, s2c = 1.f - s2;
    float t0 = s0 * s1, t1 = s0c * s1, t2 = s0 * s1c, t3 = s0c * s1c;
    float pl[8];
    pl[0] = t0 * s2;  pl[1] = t1 * s2;  pl[2] = t2 * s2;  pl[3] = t3 * s2;
    pl[4] = t0 * s2c; pl[5] = t1 * s2c; pl[6] = t2 * s2c; pl[7] = t3 * s2c;
    float sel3 = half ? (1.f - s3) : s3;
    float Af = A * sel3;
    float s4c = 1.f - s4, s5c = 1.f - s5;
    float as6 = Af * s6, as6c = Af * (1.f - s6);
    float u0 = s4 * s5, u1 = s4c * s5, u2 = s4 * s5c, u3 = s4c * s5c;
    float wv[8];
    wv[0] = u0 * as6;  wv[1] = u1 * as6;  wv[2] = u2 * as6;  wv[3] = u3 * as6;
    wv[4] = u0 * as6c; wv[5] = u1 * as6c; wv[6] = u2 * as6c; wv[7] = u3 * as6c;

    __half2 pl2[4];
#pragma unroll
    for (int jp = 0; jp < 4; ++jp)
      pl2[jp] = __float22half2_rn(make_float2(pl[jp * 2], pl[jp * 2 + 1]));

#pragma unroll
    for (int s = 0; s < 8; ++s) {
      __half2 w2 = __half2half2(__float2half(wv[s]));
      union { short8 v; __half2 h[4]; } a;
#pragma unroll
      for (int jp = 0; jp < 4; ++jp) a.h[jp] = __hmul2(pl2[jp], w2);
      acc = __builtin_amdgcn_mfma_f32_32x32x16_f16(
          a.v, *(const short8*)&bf[s], acc, 0, 0, 0);
    }
  }

  const int col = lane & 31;
  if (col < CC) {
#pragma unroll
    for (int r = 0; r < 16; ++r) {
      int row = (r & 3) + 8 * (r >> 2) + 4 * half;
      red[(w * 32 + row) * 10 + col] = acc[r];
    }
  }
  __syncthreads();
#pragma unroll
  for (int j = 0; j < 5; ++j) {
    int idx = tid + 256 * j;   // 0..1279
    partial[(size_t)tg * 81920 + (size_t)bg * 1280 + idx] = red[idx];
  }
}

// ---------------- Kernel 4: final reduce over 16 tree-groups ----------------
__global__ __launch_bounds__(256) void reduce_kernel(
    const float* __restrict__ partial, float* __restrict__ out) {
  int idx = blockIdx.x * 256 + threadIdx.x;  // 0..81919
  float s = 0.f;
#pragma unroll
  for (int tg = 0; tg < 16; ++tg) s += partial[(size_t)tg * 81920 + idx];
  out[idx] = s;
}

// ---------------------------------------------------------------------------
extern "C" void kernel_launch(void* const* d_in, const int* in_sizes, int n_in,
                              void* d_out, int out_size, void* d_ws, size_t ws_size,
                              hipStream_t stream) {
  const float* x    = (const float*)d_in[0];
  const float* mask = (const float*)d_in[1];
  const float* thr  = (const float*)d_in[2];
  const float* lo   = (const float*)d_in[3];
  const float* W1   = (const float*)d_in[4];
  const float* b1   = (const float*)d_in[5];
  const float* W2   = (const float*)d_in[6];
  const float* b2   = (const float*)d_in[7];
  float* out = (float*)d_out;
  float* ws  = (float*)d_ws;

  __half*       sPack   = (__half*)(ws + OFF_SP);
  __half*       attnB   = (__half*)(ws + OFF_AT);
  unsigned int* LPb     = (unsigned int*)(ws + OFF_LPB);
  float*        partial = ws + OFF_PT;

  zs_kernel<<<dim3(32, 32), 256, 0, stream>>>(mask, x, thr, sPack);
  attn_prep_kernel<<<128, 256, 0, stream>>>(x, lo, W1, b1, W2, b2, attnB, LPb);
  main_kernel<<<dim3(64, 16), 256, 0, stream>>>(sPack, attnB, LPb, partial);
  reduce_kernel<<<320, 256, 0, stream>>>(partial, out);
}

// Round 12
// 118.163 us; speedup vs baseline: 1.0538x; 1.0538x over previous
//
#include <hip/hip_runtime.h>
#include <hip/hip_bf16.h>
#include <hip/hip_fp16.h>

// Problem: B=8192, T=128, D=7, I=128, C=10, H=64, L=128
// ws layout (float slots):
//   sTh   fp16 [896][8192]     off 0          (3,670,016)
//   attnB fp16 [8192][128]     off 3,670,016  (524,288)
//   sPack fp16 [128][8192][8]  off 4,194,304  (4,194,304)  d0..6 = s, d7 = 0
//   LPb   fp16 B-frags         off 8,388,608  (262,144)
//   partial [16][8192][10]     off 8,650,752  (1,310,720)
// total 9,961,472 floats = 39.85 MB

#define BB 8192
#define TT 128
#define II 128
#define CC 10
#define HH 64

#define OFF_STH 0
#define OFF_AT  3670016
#define OFF_SP  4194304
#define OFF_LPB 8388608
#define OFF_PT  8650752

typedef __attribute__((ext_vector_type(8))) short short8;
typedef __attribute__((ext_vector_type(16))) float floatx16;

static __device__ inline unsigned int pkbf(float lo, float hi) {
  __hip_bfloat162 h = __float22bfloat162_rn(make_float2(lo, hi));
  unsigned int u;
  __builtin_memcpy(&u, &h, 4);
  return u;
}

static __device__ inline unsigned int pkh(float lo, float hi) {
  __half2 h = __float22half2_rn(make_float2(lo, hi));
  unsigned int u;
  __builtin_memcpy(&u, &h, 4);
  return u;
}

static __device__ inline short8 cvt8(float4 a, float4 b) {
  union { short8 v; unsigned int u[4]; } r;
  r.u[0] = pkbf(a.x, a.y);
  r.u[1] = pkbf(a.z, a.w);
  r.u[2] = pkbf(b.x, b.y);
  r.u[3] = pkbf(b.z, b.w);
  return r.v;
}

// ---------------- Phase 1: fused attn (MFMA) + zs (MFMA) + prep -------------
// blocks [0,64): attn | [64,960): zs | [960,1024): prep
// Fusion is deliberate: attn blocks overlap with zs blocks (R11's split
// serialized them, +6us). LDS shrunk to 18.4KB by storing hids as bf16
// (was 34.8KB fp32 -> capped the WHOLE kernel at 4 blocks/CU; R11 diagnosis).
// (256,2): attn branch needs the full unified-reg budget (R7: (256,4)
// spilled, +18us). All stores coalesced (R9: sPack scatter cost 2x writes).
__global__ __launch_bounds__(256, 2) void phase1_kernel(
    const float* __restrict__ x, const float* __restrict__ mask,
    const float* __restrict__ thr, const float* __restrict__ lo,
    const float* __restrict__ W1, const float* __restrict__ b1,
    const float* __restrict__ W2, const float* __restrict__ b2,
    __half* __restrict__ sTh, __half* __restrict__ attnB,
    unsigned int* __restrict__ lpb) {
  __shared__ __align__(16) char smem_raw[18432];   // 18 KB
  const int blk = blockIdx.x;
  const int tid = threadIdx.x;
  const int wv = tid >> 6, lane = tid & 63;
  const int half = lane >> 5, l31 = lane & 31;

  if (blk < 64) {
    // ---------------- attn branch: 128 b-rows/block, 32/wave ----------------
    const int b0 = blk * 128 + wv * 32;

    short8 axf[8];
    const float* xrow = x + (size_t)(b0 + l31) * II + half * 8;
#pragma unroll
    for (int s = 0; s < 8; ++s)
      axf[s] = cvt8(*(const float4*)(xrow + s * 16),
                    *(const float4*)(xrow + s * 16 + 4));

    // hidden = relu(x@W1 + b1): 2 n-tiles x 8 k-slices
    floatx16 acch[2];
#pragma unroll
    for (int i = 0; i < 16; ++i) { acch[0][i] = 0.f; acch[1][i] = 0.f; }
#pragma unroll
    for (int s = 0; s < 8; ++s) {
#pragma unroll
      for (int tile = 0; tile < 2; ++tile) {
        union { short8 v; unsigned int u[4]; } wf;
#pragma unroll
        for (int jp = 0; jp < 4; ++jp) {
          int k0 = s * 16 + half * 8 + jp * 2;
          float f0 = W1[(size_t)k0 * HH + tile * 32 + l31];
          float f1 = W1[(size_t)(k0 + 1) * HH + tile * 32 + l31];
          wf.u[jp] = pkbf(f0, f1);
        }
        acch[tile] = __builtin_amdgcn_mfma_f32_32x32x16_bf16(
            axf[s], wf.v, acch[tile], 0, 0, 0);
      }
    }
    // bias + relu -> bf16 LDS [row][h], stride 72 halves (144B, 16B-aligned)
    __hip_bfloat16* hids = (__hip_bfloat16*)smem_raw + wv * (32 * 72);
#pragma unroll
    for (int tile = 0; tile < 2; ++tile) {
      float bh = b1[tile * 32 + l31];
#pragma unroll
      for (int r = 0; r < 16; ++r) {
        int row = (r & 3) + 8 * (r >> 2) + 4 * half;
        hids[row * 72 + tile * 32 + l31] =
            __float2bfloat16(fmaxf(acch[tile][r] + bh, 0.f));
      }
    }
    __syncthreads();

    // hidden A-frags: direct short8 reads (no cvt)
    short8 ahf[4];
#pragma unroll
    for (int s = 0; s < 4; ++s)
      ahf[s] = *(const short8*)(hids + l31 * 72 + s * 16 + half * 8);

    // logits = hidden@W2 + b2: 4 n-tiles x 4 k-slices
    floatx16 accl[4];
#pragma unroll
    for (int tile = 0; tile < 4; ++tile) {
#pragma unroll
      for (int i = 0; i < 16; ++i) accl[tile][i] = 0.f;
#pragma unroll
      for (int s = 0; s < 4; ++s) {
        union { short8 v; unsigned int u[4]; } wf;
#pragma unroll
        for (int jp = 0; jp < 4; ++jp) {
          int k0 = s * 16 + half * 8 + jp * 2;
          float f0 = W2[(size_t)k0 * TT + tile * 32 + l31];
          float f1 = W2[(size_t)(k0 + 1) * TT + tile * 32 + l31];
          wf.u[jp] = pkbf(f0, f1);
        }
        accl[tile] = __builtin_amdgcn_mfma_f32_32x32x16_bf16(
            ahf[s], wf.v, accl[tile], 0, 0, 0);
      }
      float bt = b2[tile * 32 + l31];
#pragma unroll
      for (int i = 0; i < 16; ++i) accl[tile][i] += bt;
    }

    // softmax over t, butterfly reduce
    float mrow[16];
#pragma unroll
    for (int r = 0; r < 16; ++r)
      mrow[r] = fmaxf(fmaxf(accl[0][r], accl[1][r]),
                      fmaxf(accl[2][r], accl[3][r]));
#pragma unroll
    for (int msk = 1; msk <= 16; msk <<= 1)
#pragma unroll
      for (int r = 0; r < 16; ++r)
        mrow[r] = fmaxf(mrow[r], __shfl_xor(mrow[r], msk, 64));
    float srow[16];
#pragma unroll
    for (int r = 0; r < 16; ++r) srow[r] = 0.f;
#pragma unroll
    for (int tile = 0; tile < 4; ++tile)
#pragma unroll
      for (int r = 0; r < 16; ++r) {
        float e = __expf(accl[tile][r] - mrow[r]);
        accl[tile][r] = e;
        srow[r] += e;
      }
#pragma unroll
    for (int msk = 1; msk <= 16; msk <<= 1)
#pragma unroll
      for (int r = 0; r < 16; ++r)
        srow[r] += __shfl_xor(srow[r], msk, 64);
#pragma unroll
    for (int r = 0; r < 16; ++r) srow[r] = 1.f / srow[r];

    // store attnB[b][t] fp16 (lanes consecutive t -> coalesced)
#pragma unroll
    for (int tile = 0; tile < 4; ++tile)
#pragma unroll
      for (int r = 0; r < 16; ++r) {
        int row = (r & 3) + 8 * (r >> 2) + 4 * half;
        attnB[(size_t)(b0 + row) * TT + tile * 32 + l31] =
            __float2half(accl[tile][r] * srow[r]);
      }

  } else if (blk < 960) {
    // ---------------- zs branch (MFMA, no LDS) -> sTh[td][b] coalesced ------
    const int blk2 = blk - 64;
    const int mb = blk2 >> 5;       // 0..27
    const int ns = blk2 & 31;       // 0..31
    const int m0 = mb * 32;

    short8 af[8];
    const float* mrow = mask + (size_t)(m0 + l31) * II + half * 8;
#pragma unroll
    for (int s = 0; s < 8; ++s)
      af[s] = cvt8(*(const float4*)(mrow + s * 16),
                   *(const float4*)(mrow + s * 16 + 4));
    float th[16];
#pragma unroll
    for (int r = 0; r < 16; ++r)
      th[r] = thr[m0 + (r & 3) + 8 * (r >> 2) + 4 * half];

#pragma unroll
    for (int nb = 0; nb < 2; ++nb) {
      const int n0 = ns * 256 + wv * 64 + nb * 32;
      const float* xrow = x + (size_t)(n0 + l31) * II + half * 8;
      floatx16 acc;
#pragma unroll
      for (int i = 0; i < 16; ++i) acc[i] = 0.f;
#pragma unroll
      for (int s = 0; s < 8; ++s) {
        short8 bf = cvt8(*(const float4*)(xrow + s * 16),
                         *(const float4*)(xrow + s * 16 + 4));
        acc = __builtin_amdgcn_mfma_f32_32x32x16_bf16(af[s], bf, acc, 0, 0, 0);
      }
#pragma unroll
      for (int r = 0; r < 16; ++r) {
        int row = (r & 3) + 8 * (r >> 2) + 4 * half;
        float z = acc[r] - th[r];
        float o = 0.5f * (z / (1.f + fabsf(z)) + 1.f);
        sTh[(size_t)(m0 + row) * BB + n0 + l31] = __float2half(o);
      }
    }

  } else {
    // ---------------- prep branch: leaf softmax -> fp16 B-frags -------------
    float* lps = (float*)smem_raw;   // 3072 floats = 12KB < 18KB
    const int t0 = (blk - 960) * 2;
    {
      int tl = tid >> 7, l = tid & 127;
      const float* row = lo + ((size_t)(t0 + tl) * 128 + l) * CC;
      float v[CC];
      float m = -1e30f;
#pragma unroll
      for (int c = 0; c < CC; ++c) { v[c] = row[c]; m = fmaxf(m, v[c]); }
      float s = 0.f;
#pragma unroll
      for (int c = 0; c < CC; ++c) { v[c] = __expf(v[c] - m); s += v[c]; }
      float inv = 1.f / s;
      float* o = lps + (tl * 128 + l) * 12;
#pragma unroll
      for (int c = 0; c < CC; ++c) o[c] = v[c] * inv;
      o[10] = 0.f; o[11] = 0.f;
    }
    __syncthreads();

#pragma unroll
    for (int jj = 0; jj < 4; ++jj) {
      int idx = tid + 256 * jj;           // 0..1023 = (tl, s, lane)
      int tl = idx >> 9, rem = idx & 511;
      int s = rem >> 6, ln = rem & 63;
      int hf = ln >> 5, n = ln & 31;
      unsigned int wd[4];
#pragma unroll
      for (int jp = 0; jp < 4; ++jp) {
        int l0 = s * 16 + hf * 8 + jp * 2;
        float f0 = (n < CC) ? lps[(tl * 128 + l0) * 12 + n] : 0.f;
        float f1 = (n < CC) ? lps[(tl * 128 + l0 + 1) * 12 + n] : 0.f;
        wd[jp] = pkh(f0, f1);
      }
      ((uint4*)lpb)[(size_t)(t0 + tl) * 512 + s * 64 + ln] =
          make_uint4(wd[0], wd[1], wd[2], wd[3]);
    }
  }
}

// ---------------- Kernel 1b: repack sTh -> sPack[t][b][8] -------------------
// Coalesced both ways: 7x 2B loads (lanes = consecutive b), one uint4 store.
__global__ __launch_bounds__(256) void repack_kernel(
    const __half* __restrict__ sTh, __half* __restrict__ sPack) {
  int idx = blockIdx.x * 256 + threadIdx.x;   // 0..1048575
  int b = idx & (BB - 1);
  int t = idx >> 13;
  union { uint4 v; __half h[8]; } p;
#pragma unroll
  for (int d = 0; d < 7; ++d)
    p.h[d] = sTh[(size_t)(t * 7 + d) * BB + b];
  p.h[7] = __float2half(0.f);
  ((uint4*)sPack)[(size_t)t * BB + b] = p.v;
}

// ---------------- Kernel 2: main contraction via MFMA (fp16) ----------------
// grid (64 bg of 128 b, 16 tg of 8 trees); block 256 = 4 waves.
// Per t-iter: ONE coalesced dwordx4 gives s0..s6 (sv double-buffered);
// attn for all 8 trees from one attnB uint4. a-frags via __hmul2.
__global__ __launch_bounds__(256, 4) void main_kernel(
    const __half* __restrict__ sPack, const __half* __restrict__ attnB,
    const unsigned int* __restrict__ lpb, float* __restrict__ partial) {
  __shared__ float red[128 * 10];
  const int bg = blockIdx.x, tg = blockIdx.y;
  const int tid = threadIdx.x;
  const int w = tid >> 6, lane = tid & 63;
  const int half = lane >> 5;
  const int b = bg * 128 + w * 32 + (lane & 31);
  const uint4* spk = (const uint4*)sPack;

  __half av[8];
  *(uint4*)av = *(const uint4*)(attnB + (size_t)b * TT + tg * 8);

  floatx16 acc;
#pragma unroll
  for (int i = 0; i < 16; ++i) acc[i] = 0.f;

  uint4 sv[2];
  sv[0] = spk[(size_t)(tg * 8) * BB + b];

#pragma unroll
  for (int it = 0; it < 8; ++it) {
    const int cur = it & 1;
    const int t = tg * 8 + it;
    uint4 bf[8];
    const uint4* lpt = (const uint4*)lpb + (size_t)t * 512 + lane;
#pragma unroll
    for (int s = 0; s < 8; ++s) bf[s] = lpt[s * 64];
    if (it < 7) sv[cur ^ 1] = spk[(size_t)(t + 1) * BB + b];

    const __half* sh = (const __half*)&sv[cur];
    float s0 = __half2float(sh[0]), s1 = __half2float(sh[1]);
    float s2 = __half2float(sh[2]), s3 = __half2float(sh[3]);
    float s4 = __half2float(sh[4]), s5 = __half2float(sh[5]);
    float s6 = __half2float(sh[6]);
    float A  = __half2float(av[it]);

    float s0c = 1.f - s0, s1c = 1.f - s1, s2c = 1.f - s2;
    float t0 = s0 * s1, t1 = s0c * s1, t2 = s0 * s1c, t3 = s0c * s1c;
    float pl[8];
    pl[0] = t0 * s2;  pl[1] = t1 * s2;  pl[2] = t2 * s2;  pl[3] = t3 * s2;
    pl[4] = t0 * s2c; pl[5] = t1 * s2c; pl[6] = t2 * s2c; pl[7] = t3 * s2c;
    float sel3 = half ? (1.f - s3) : s3;
    float Af = A * sel3;
    float s4c = 1.f - s4, s5c = 1.f - s5;
    float as6 = Af * s6, as6c = Af * (1.f - s6);
    float u0 = s4 * s5, u1 = s4c * s5, u2 = s4 * s5c, u3 = s4c * s5c;
    float wv[8];
    wv[0] = u0 * as6;  wv[1] = u1 * as6;  wv[2] = u2 * as6;  wv[3] = u3 * as6;
    wv[4] = u0 * as6c; wv[5] = u1 * as6c; wv[6] = u2 * as6c; wv[7] = u3 * as6c;

    __half2 pl2[4];
#pragma unroll
    for (int jp = 0; jp < 4; ++jp)
      pl2[jp] = __float22half2_rn(make_float2(pl[jp * 2], pl[jp * 2 + 1]));

#pragma unroll
    for (int s = 0; s < 8; ++s) {
      __half2 w2 = __half2half2(__float2half(wv[s]));
      union { short8 v; __half2 h[4]; } a;
#pragma unroll
      for (int jp = 0; jp < 4; ++jp) a.h[jp] = __hmul2(pl2[jp], w2);
      acc = __builtin_amdgcn_mfma_f32_32x32x16_f16(
          a.v, *(const short8*)&bf[s], acc, 0, 0, 0);
    }
  }

  const int col = lane & 31;
  if (col < CC) {
#pragma unroll
    for (int r = 0; r < 16; ++r) {
      int row = (r & 3) + 8 * (r >> 2) + 4 * half;
      red[(w * 32 + row) * 10 + col] = acc[r];
    }
  }
  __syncthreads();
#pragma unroll
  for (int j = 0; j < 5; ++j) {
    int idx = tid + 256 * j;   // 0..1279
    partial[(size_t)tg * 81920 + (size_t)bg * 1280 + idx] = red[idx];
  }
}

// ---------------- Kernel 3: final reduce over 16 tree-groups ----------------
__global__ __launch_bounds__(256) void reduce_kernel(
    const float* __restrict__ partial, float* __restrict__ out) {
  int idx = blockIdx.x * 256 + threadIdx.x;  // 0..81919
  float s = 0.f;
#pragma unroll
  for (int tg = 0; tg < 16; ++tg) s += partial[(size_t)tg * 81920 + idx];
  out[idx] = s;
}

// ---------------------------------------------------------------------------
extern "C" void kernel_launch(void* const* d_in, const int* in_sizes, int n_in,
                              void* d_out, int out_size, void* d_ws, size_t ws_size,
                              hipStream_t stream) {
  const float* x    = (const float*)d_in[0];
  const float* mask = (const float*)d_in[1];
  const float* thr  = (const float*)d_in[2];
  const float* lo   = (const float*)d_in[3];
  const float* W1   = (const float*)d_in[4];
  const float* b1   = (const float*)d_in[5];
  const float* W2   = (const float*)d_in[6];
  const float* b2   = (const float*)d_in[7];
  float* out = (float*)d_out;
  float* ws  = (float*)d_ws;

  __half*       sTh     = (__half*)(ws + OFF_STH);
  __half*       attnB   = (__half*)(ws + OFF_AT);
  __half*       sPack   = (__half*)(ws + OFF_SP);
  unsigned int* LPb     = (unsigned int*)(ws + OFF_LPB);
  float*        partial = ws + OFF_PT;

  phase1_kernel<<<1024, 256, 0, stream>>>(x, mask, thr, lo, W1, b1, W2, b2,
                                          sTh, attnB, LPb);
  repack_kernel<<<4096, 256, 0, stream>>>(sTh, sPack);
  main_kernel<<<dim3(64, 16), 256, 0, stream>>>(sPack, attnB, LPb, partial);
  reduce_kernel<<<320, 256, 0, stream>>>(partial, out);
}

// Round 13
// 117.443 us; speedup vs baseline: 1.0603x; 1.0061x over previous
//
#include <hip/hip_runtime.h>
#include <hip/hip_bf16.h>
#include <hip/hip_fp16.h>

// Problem: B=8192, T=128, D=7, I=128, C=10, H=64, L=128
// ws layout (float slots):
//   sPack fp16 [128][8192][8]  off 0          (4,194,304)  d0..6 = s, d7 = junk
//   attnB fp16 [8192][128]     off 4,194,304  (524,288)
//   LPb   fp16 B-frags         off 4,718,592  (262,144)
//   partial [16][8192][10]     off 4,980,736  (1,310,720)
// total 6,291,456 floats = 25.2 MB

#define BB 8192
#define TT 128
#define II 128
#define CC 10
#define HH 64

#define OFF_SP  0
#define OFF_AT  4194304
#define OFF_LPB 4718592
#define OFF_PT  4980736

typedef __attribute__((ext_vector_type(8))) short short8;
typedef __attribute__((ext_vector_type(16))) float floatx16;

static __device__ inline unsigned int pkbf(float lo, float hi) {
  __hip_bfloat162 h = __float22bfloat162_rn(make_float2(lo, hi));
  unsigned int u;
  __builtin_memcpy(&u, &h, 4);
  return u;
}

static __device__ inline unsigned int pkh(float lo, float hi) {
  __half2 h = __float22half2_rn(make_float2(lo, hi));
  unsigned int u;
  __builtin_memcpy(&u, &h, 4);
  return u;
}

static __device__ inline short8 cvt8(float4 a, float4 b) {
  union { short8 v; unsigned int u[4]; } r;
  r.u[0] = pkbf(a.x, a.y);
  r.u[1] = pkbf(a.z, a.w);
  r.u[2] = pkbf(b.x, b.y);
  r.u[3] = pkbf(b.z, b.w);
  return r.v;
}

// ---------------- Phase 1: fused attn (MFMA) + zs (MFMA) + prep -------------
// blocks [0,64): attn | [64,1088): zs | [1088,1152): prep
// Fusion is deliberate: attn blocks overlap with zs blocks (R11's SPLIT
// serialized them, +6us — the loss was the split, not the transpose).
// zs writes sPack DIRECTLY via 16KB-LDS transpose (28-row tiles = 4 whole
// trees/block) -> kills the repack kernel + sTh round-trip (R13).
// (256,2): attn branch needs the full unified-reg budget (R7: (256,4)
// spilled, +18us). All global stores coalesced (R9: scatter cost 2x writes).
__global__ __launch_bounds__(256, 2) void phase1_kernel(
    const float* __restrict__ x, const float* __restrict__ mask,
    const float* __restrict__ thr, const float* __restrict__ lo,
    const float* __restrict__ W1, const float* __restrict__ b1,
    const float* __restrict__ W2, const float* __restrict__ b2,
    __half* __restrict__ sPack, __half* __restrict__ attnB,
    unsigned int* __restrict__ lpb) {
  __shared__ __align__(16) char smem_raw[18432];   // 18 KB
  const int blk = blockIdx.x;
  const int tid = threadIdx.x;
  const int wv = tid >> 6, lane = tid & 63;
  const int half = lane >> 5, l31 = lane & 31;

  if (blk < 64) {
    // ---------------- attn branch: 128 b-rows/block, 32/wave ----------------
    const int b0 = blk * 128 + wv * 32;

    short8 axf[8];
    const float* xrow = x + (size_t)(b0 + l31) * II + half * 8;
#pragma unroll
    for (int s = 0; s < 8; ++s)
      axf[s] = cvt8(*(const float4*)(xrow + s * 16),
                    *(const float4*)(xrow + s * 16 + 4));

    // hidden = relu(x@W1 + b1): 2 n-tiles x 8 k-slices
    floatx16 acch[2];
#pragma unroll
    for (int i = 0; i < 16; ++i) { acch[0][i] = 0.f; acch[1][i] = 0.f; }
#pragma unroll
    for (int s = 0; s < 8; ++s) {
#pragma unroll
      for (int tile = 0; tile < 2; ++tile) {
        union { short8 v; unsigned int u[4]; } wf;
#pragma unroll
        for (int jp = 0; jp < 4; ++jp) {
          int k0 = s * 16 + half * 8 + jp * 2;
          float f0 = W1[(size_t)k0 * HH + tile * 32 + l31];
          float f1 = W1[(size_t)(k0 + 1) * HH + tile * 32 + l31];
          wf.u[jp] = pkbf(f0, f1);
        }
        acch[tile] = __builtin_amdgcn_mfma_f32_32x32x16_bf16(
            axf[s], wf.v, acch[tile], 0, 0, 0);
      }
    }
    // bias + relu -> bf16 LDS [row][h], stride 72 halves (144B, 16B-aligned)
    __hip_bfloat16* hids = (__hip_bfloat16*)smem_raw + wv * (32 * 72);
#pragma unroll
    for (int tile = 0; tile < 2; ++tile) {
      float bh = b1[tile * 32 + l31];
#pragma unroll
      for (int r = 0; r < 16; ++r) {
        int row = (r & 3) + 8 * (r >> 2) + 4 * half;
        hids[row * 72 + tile * 32 + l31] =
            __float2bfloat16(fmaxf(acch[tile][r] + bh, 0.f));
      }
    }
    __syncthreads();

    // hidden A-frags: direct short8 reads (no cvt)
    short8 ahf[4];
#pragma unroll
    for (int s = 0; s < 4; ++s)
      ahf[s] = *(const short8*)(hids + l31 * 72 + s * 16 + half * 8);

    // logits = hidden@W2 + b2: 4 n-tiles x 4 k-slices
    floatx16 accl[4];
#pragma unroll
    for (int tile = 0; tile < 4; ++tile) {
#pragma unroll
      for (int i = 0; i < 16; ++i) accl[tile][i] = 0.f;
#pragma unroll
      for (int s = 0; s < 4; ++s) {
        union { short8 v; unsigned int u[4]; } wf;
#pragma unroll
        for (int jp = 0; jp < 4; ++jp) {
          int k0 = s * 16 + half * 8 + jp * 2;
          float f0 = W2[(size_t)k0 * TT + tile * 32 + l31];
          float f1 = W2[(size_t)(k0 + 1) * TT + tile * 32 + l31];
          wf.u[jp] = pkbf(f0, f1);
        }
        accl[tile] = __builtin_amdgcn_mfma_f32_32x32x16_bf16(
            ahf[s], wf.v, accl[tile], 0, 0, 0);
      }
      float bt = b2[tile * 32 + l31];
#pragma unroll
      for (int i = 0; i < 16; ++i) accl[tile][i] += bt;
    }

    // softmax over t, butterfly reduce
    float mrow[16];
#pragma unroll
    for (int r = 0; r < 16; ++r)
      mrow[r] = fmaxf(fmaxf(accl[0][r], accl[1][r]),
                      fmaxf(accl[2][r], accl[3][r]));
#pragma unroll
    for (int msk = 1; msk <= 16; msk <<= 1)
#pragma unroll
      for (int r = 0; r < 16; ++r)
        mrow[r] = fmaxf(mrow[r], __shfl_xor(mrow[r], msk, 64));
    float srow[16];
#pragma unroll
    for (int r = 0; r < 16; ++r) srow[r] = 0.f;
#pragma unroll
    for (int tile = 0; tile < 4; ++tile)
#pragma unroll
      for (int r = 0; r < 16; ++r) {
        float e = __expf(accl[tile][r] - mrow[r]);
        accl[tile][r] = e;
        srow[r] += e;
      }
#pragma unroll
    for (int msk = 1; msk <= 16; msk <<= 1)
#pragma unroll
      for (int r = 0; r < 16; ++r)
        srow[r] += __shfl_xor(srow[r], msk, 64);
#pragma unroll
    for (int r = 0; r < 16; ++r) srow[r] = 1.f / srow[r];

    // store attnB[b][t] fp16 (lanes consecutive t -> coalesced)
#pragma unroll
    for (int tile = 0; tile < 4; ++tile)
#pragma unroll
      for (int r = 0; r < 16; ++r) {
        int row = (r & 3) + 8 * (r >> 2) + 4 * half;
        attnB[(size_t)(b0 + row) * TT + tile * 32 + l31] =
            __float2half(accl[tile][r] * srow[r]);
      }

  } else if (blk < 1088) {
    // ------- zs branch (MFMA) -> sPack via LDS transpose, coalesced ---------
    // Tile = rows m0..m0+31, m0 = mb*28 -> trees 4mb..4mb+3 complete in-tile
    // (rows 28..31 discarded; OOB rows clamped).
    __half* lds = (__half*)smem_raw;       // [tree_local][b_local][8] = 16 KB
    const int blk2 = blk - 64;
    const int mb = blk2 >> 5;              // 0..31
    const int ns = blk2 & 31;              // 0..31, 256 b each
    const int m0 = mb * 28;

    int mr = m0 + l31; if (mr > 895) mr = 895;
    const float* mrow = mask + (size_t)mr * II + half * 8;
    short8 af[8];
#pragma unroll
    for (int s = 0; s < 8; ++s)
      af[s] = cvt8(*(const float4*)(mrow + s * 16),
                   *(const float4*)(mrow + s * 16 + 4));
    float th[16];
#pragma unroll
    for (int r = 0; r < 16; ++r) {
      int m = m0 + (r & 3) + 8 * (r >> 2) + 4 * half;
      th[r] = thr[m > 895 ? 895 : m];
    }

#pragma unroll
    for (int nb = 0; nb < 2; ++nb) {
      const int nl = wv * 64 + nb * 32;    // b_local of this 32-tile
      const float* xrow = x + (size_t)(ns * 256 + nl + l31) * II + half * 8;
      floatx16 acc;
#pragma unroll
      for (int i = 0; i < 16; ++i) acc[i] = 0.f;
#pragma unroll
      for (int s = 0; s < 8; ++s) {
        short8 bf = cvt8(*(const float4*)(xrow + s * 16),
                         *(const float4*)(xrow + s * 16 + 4));
        acc = __builtin_amdgcn_mfma_f32_32x32x16_bf16(af[s], bf, acc, 0, 0, 0);
      }
#pragma unroll
      for (int r = 0; r < 16; ++r) {
        int row = (r & 3) + 8 * (r >> 2) + 4 * half;   // 0..31
        if (row < 28) {
          int tl = row / 7;                // tree_local 0..3
          int d = row - tl * 7;
          float z = acc[r] - th[r];
          float o = 0.5f * (z / (1.f + fabsf(z)) + 1.f);
          lds[(tl * 256 + nl + l31) * 8 + d] = __float2half(o);
        }
      }
    }
    __syncthreads();

    // coalesced store: 4 uint4/thread; slot 7 junk (never read by main)
    const uint4* l4 = (const uint4*)lds;
#pragma unroll
    for (int j = 0; j < 4; ++j) {
      int idx = tid + 256 * j;             // tree = idx>>8, bl = idx&255
      ((uint4*)sPack)[(size_t)(4 * mb + (idx >> 8)) * BB + ns * 256 + (idx & 255)] =
          l4[idx];
    }

  } else {
    // ---------------- prep branch: leaf softmax -> fp16 B-frags -------------
    float* lps = (float*)smem_raw;   // 3072 floats = 12KB < 18KB
    const int t0 = (blk - 1088) * 2;
    {
      int tl = tid >> 7, l = tid & 127;
      const float* row = lo + ((size_t)(t0 + tl) * 128 + l) * CC;
      float v[CC];
      float m = -1e30f;
#pragma unroll
      for (int c = 0; c < CC; ++c) { v[c] = row[c]; m = fmaxf(m, v[c]); }
      float s = 0.f;
#pragma unroll
      for (int c = 0; c < CC; ++c) { v[c] = __expf(v[c] - m); s += v[c]; }
      float inv = 1.f / s;
      float* o = lps + (tl * 128 + l) * 12;
#pragma unroll
      for (int c = 0; c < CC; ++c) o[c] = v[c] * inv;
      o[10] = 0.f; o[11] = 0.f;
    }
    __syncthreads();

#pragma unroll
    for (int jj = 0; jj < 4; ++jj) {
      int idx = tid + 256 * jj;           // 0..1023 = (tl, s, lane)
      int tl = idx >> 9, rem = idx & 511;
      int s = rem >> 6, ln = rem & 63;
      int hf = ln >> 5, n = ln & 31;
      unsigned int wd[4];
#pragma unroll
      for (int jp = 0; jp < 4; ++jp) {
        int l0 = s * 16 + hf * 8 + jp * 2;
        float f0 = (n < CC) ? lps[(tl * 128 + l0) * 12 + n] : 0.f;
        float f1 = (n < CC) ? lps[(tl * 128 + l0 + 1) * 12 + n] : 0.f;
        wd[jp] = pkh(f0, f1);
      }
      ((uint4*)lpb)[(size_t)(t0 + tl) * 512 + s * 64 + ln] =
          make_uint4(wd[0], wd[1], wd[2], wd[3]);
    }
  }
}

// ---------------- Kernel 2: main contraction via MFMA (fp16) ----------------
// grid (64 bg of 128 b, 16 tg of 8 trees); block 256 = 4 waves.
// Per t-iter: ONE coalesced dwordx4 gives s0..s6 (sv double-buffered);
// attn for all 8 trees from one attnB uint4. a-frags via __hmul2.
__global__ __launch_bounds__(256, 4) void main_kernel(
    const __half* __restrict__ sPack, const __half* __restrict__ attnB,
    const unsigned int* __restrict__ lpb, float* __restrict__ partial) {
  __shared__ float red[128 * 10];
  const int bg = blockIdx.x, tg = blockIdx.y;
  const int tid = threadIdx.x;
  const int w = tid >> 6, lane = tid & 63;
  const int half = lane >> 5;
  const int b = bg * 128 + w * 32 + (lane & 31);
  const uint4* spk = (const uint4*)sPack;

  __half av[8];
  *(uint4*)av = *(const uint4*)(attnB + (size_t)b * TT + tg * 8);

  floatx16 acc;
#pragma unroll
  for (int i = 0; i < 16; ++i) acc[i] = 0.f;

  uint4 sv[2];
  sv[0] = spk[(size_t)(tg * 8) * BB + b];

#pragma unroll
  for (int it = 0; it < 8; ++it) {
    const int cur = it & 1;
    const int t = tg * 8 + it;
    uint4 bf[8];
    const uint4* lpt = (const uint4*)lpb + (size_t)t * 512 + lane;
#pragma unroll
    for (int s = 0; s < 8; ++s) bf[s] = lpt[s * 64];
    if (it < 7) sv[cur ^ 1] = spk[(size_t)(t + 1) * BB + b];

    const __half* sh = (const __half*)&sv[cur];
    float s0 = __half2float(sh[0]), s1 = __half2float(sh[1]);
    float s2 = __half2float(sh[2]), s3 = __half2float(sh[3]);
    float s4 = __half2float(sh[4]), s5 = __half2float(sh[5]);
    float s6 = __half2float(sh[6]);
    float A  = __half2float(av[it]);

    float s0c = 1.f - s0, s1c = 1.f - s1, s2c = 1.f - s2;
    float t0 = s0 * s1, t1 = s0c * s1, t2 = s0 * s1c, t3 = s0c * s1c;
    float pl[8];
    pl[0] = t0 * s2;  pl[1] = t1 * s2;  pl[2] = t2 * s2;  pl[3] = t3 * s2;
    pl[4] = t0 * s2c; pl[5] = t1 * s2c; pl[6] = t2 * s2c; pl[7] = t3 * s2c;
    float sel3 = half ? (1.f - s3) : s3;
    float Af = A * sel3;
    float s4c = 1.f - s4, s5c = 1.f - s5;
    float as6 = Af * s6, as6c = Af * (1.f - s6);
    float u0 = s4 * s5, u1 = s4c * s5, u2 = s4 * s5c, u3 = s4c * s5c;
    float wv[8];
    wv[0] = u0 * as6;  wv[1] = u1 * as6;  wv[2] = u2 * as6;  wv[3] = u3 * as6;
    wv[4] = u0 * as6c; wv[5] = u1 * as6c; wv[6] = u2 * as6c; wv[7] = u3 * as6c;

    __half2 pl2[4];
#pragma unroll
    for (int jp = 0; jp < 4; ++jp)
      pl2[jp] = __float22half2_rn(make_float2(pl[jp * 2], pl[jp * 2 + 1]));

#pragma unroll
    for (int s = 0; s < 8; ++s) {
      __half2 w2 = __half2half2(__float2half(wv[s]));
      union { short8 v; __half2 h[4]; } a;
#pragma unroll
      for (int jp = 0; jp < 4; ++jp) a.h[jp] = __hmul2(pl2[jp], w2);
      acc = __builtin_amdgcn_mfma_f32_32x32x16_f16(
          a.v, *(const short8*)&bf[s], acc, 0, 0, 0);
    }
  }

  const int col = lane & 31;
  if (col < CC) {
#pragma unroll
    for (int r = 0; r < 16; ++r) {
      int row = (r & 3) + 8 * (r >> 2) + 4 * half;
      red[(w * 32 + row) * 10 + col] = acc[r];
    }
  }
  __syncthreads();
#pragma unroll
  for (int j = 0; j < 5; ++j) {
    int idx = tid + 256 * j;   // 0..1279
    partial[(size_t)tg * 81920 + (size_t)bg * 1280 + idx] = red[idx];
  }
}

// ---------------- Kernel 3: final reduce over 16 tree-groups ----------------
__global__ __launch_bounds__(256) void reduce_kernel(
    const float* __restrict__ partial, float* __restrict__ out) {
  int idx = blockIdx.x * 256 + threadIdx.x;  // 0..81919
  float s = 0.f;
#pragma unroll
  for (int tg = 0; tg < 16; ++tg) s += partial[(size_t)tg * 81920 + idx];
  out[idx] = s;
}

// ---------------------------------------------------------------------------
extern "C" void kernel_launch(void* const* d_in, const int* in_sizes, int n_in,
                              void* d_out, int out_size, void* d_ws, size_t ws_size,
                              hipStream_t stream) {
  const float* x    = (const float*)d_in[0];
  const float* mask = (const float*)d_in[1];
  const float* thr  = (const float*)d_in[2];
  const float* lo   = (const float*)d_in[3];
  const float* W1   = (const float*)d_in[4];
  const float* b1   = (const float*)d_in[5];
  const float* W2   = (const float*)d_in[6];
  const float* b2   = (const float*)d_in[7];
  float* out = (float*)d_out;
  float* ws  = (float*)d_ws;

  __half*       sPack   = (__half*)(ws + OFF_SP);
  __half*       attnB   = (__half*)(ws + OFF_AT);
  unsigned int* LPb     = (unsigned int*)(ws + OFF_LPB);
  float*        partial = ws + OFF_PT;

  phase1_kernel<<<1152, 256, 0, stream>>>(x, mask, thr, lo, W1, b1, W2, b2,
                                          sPack, attnB, LPb);
  main_kernel<<<dim3(64, 16), 256, 0, stream>>>(sPack, attnB, LPb, partial);
  reduce_kernel<<<320, 256, 0, stream>>>(partial, out);
}

// Round 14
// 110.570 us; speedup vs baseline: 1.1262x; 1.0622x over previous
//
#include <hip/hip_runtime.h>
#include <hip/hip_bf16.h>
#include <hip/hip_fp16.h>

// Problem: B=8192, T=128, D=7, I=128, C=10, H=64, L=128
// ws layout (float slots):
//   sPack fp16 [128][8192][8]  off 0          (4,194,304)  d0..6 = s, d7 = junk
//   attnB fp16 [8192][128]     off 4,194,304  (524,288)
//   LPb   fp16 B-frags         off 4,718,592  (262,144)
//   partial [16][8192][10]     off 4,980,736  (1,310,720)
// total 6,291,456 floats = 25.2 MB

#define BB 8192
#define TT 128
#define II 128
#define CC 10
#define HH 64

#define OFF_SP  0
#define OFF_AT  4194304
#define OFF_LPB 4718592
#define OFF_PT  4980736

typedef __attribute__((ext_vector_type(8))) short short8;
typedef __attribute__((ext_vector_type(16))) float floatx16;

static __device__ inline unsigned int pkbf(float lo, float hi) {
  __hip_bfloat162 h = __float22bfloat162_rn(make_float2(lo, hi));
  unsigned int u;
  __builtin_memcpy(&u, &h, 4);
  return u;
}

static __device__ inline unsigned int pkh(float lo, float hi) {
  __half2 h = __float22half2_rn(make_float2(lo, hi));
  unsigned int u;
  __builtin_memcpy(&u, &h, 4);
  return u;
}

static __device__ inline short8 cvt8(float4 a, float4 b) {
  union { short8 v; unsigned int u[4]; } r;
  r.u[0] = pkbf(a.x, a.y);
  r.u[1] = pkbf(a.z, a.w);
  r.u[2] = pkbf(b.x, b.y);
  r.u[3] = pkbf(b.z, b.w);
  return r.v;
}

// ---------------- Phase 1: fused attn (MFMA) + zs (MFMA) + prep -------------
// blocks [0,64): attn | [64,1088): zs | [1088,1152): prep  (R13 structure)
__global__ __launch_bounds__(256, 2) void phase1_kernel(
    const float* __restrict__ x, const float* __restrict__ mask,
    const float* __restrict__ thr, const float* __restrict__ lo,
    const float* __restrict__ W1, const float* __restrict__ b1,
    const float* __restrict__ W2, const float* __restrict__ b2,
    __half* __restrict__ sPack, __half* __restrict__ attnB,
    unsigned int* __restrict__ lpb) {
  __shared__ __align__(16) char smem_raw[18432];   // 18 KB
  const int blk = blockIdx.x;
  const int tid = threadIdx.x;
  const int wv = tid >> 6, lane = tid & 63;
  const int half = lane >> 5, l31 = lane & 31;

  if (blk < 64) {
    // ---------------- attn branch: 128 b-rows/block, 32/wave ----------------
    const int b0 = blk * 128 + wv * 32;

    short8 axf[8];
    const float* xrow = x + (size_t)(b0 + l31) * II + half * 8;
#pragma unroll
    for (int s = 0; s < 8; ++s)
      axf[s] = cvt8(*(const float4*)(xrow + s * 16),
                    *(const float4*)(xrow + s * 16 + 4));

    floatx16 acch[2];
#pragma unroll
    for (int i = 0; i < 16; ++i) { acch[0][i] = 0.f; acch[1][i] = 0.f; }
#pragma unroll
    for (int s = 0; s < 8; ++s) {
#pragma unroll
      for (int tile = 0; tile < 2; ++tile) {
        union { short8 v; unsigned int u[4]; } wf;
#pragma unroll
        for (int jp = 0; jp < 4; ++jp) {
          int k0 = s * 16 + half * 8 + jp * 2;
          float f0 = W1[(size_t)k0 * HH + tile * 32 + l31];
          float f1 = W1[(size_t)(k0 + 1) * HH + tile * 32 + l31];
          wf.u[jp] = pkbf(f0, f1);
        }
        acch[tile] = __builtin_amdgcn_mfma_f32_32x32x16_bf16(
            axf[s], wf.v, acch[tile], 0, 0, 0);
      }
    }
    __hip_bfloat16* hids = (__hip_bfloat16*)smem_raw + wv * (32 * 72);
#pragma unroll
    for (int tile = 0; tile < 2; ++tile) {
      float bh = b1[tile * 32 + l31];
#pragma unroll
      for (int r = 0; r < 16; ++r) {
        int row = (r & 3) + 8 * (r >> 2) + 4 * half;
        hids[row * 72 + tile * 32 + l31] =
            __float2bfloat16(fmaxf(acch[tile][r] + bh, 0.f));
      }
    }
    __syncthreads();

    short8 ahf[4];
#pragma unroll
    for (int s = 0; s < 4; ++s)
      ahf[s] = *(const short8*)(hids + l31 * 72 + s * 16 + half * 8);

    floatx16 accl[4];
#pragma unroll
    for (int tile = 0; tile < 4; ++tile) {
#pragma unroll
      for (int i = 0; i < 16; ++i) accl[tile][i] = 0.f;
#pragma unroll
      for (int s = 0; s < 4; ++s) {
        union { short8 v; unsigned int u[4]; } wf;
#pragma unroll
        for (int jp = 0; jp < 4; ++jp) {
          int k0 = s * 16 + half * 8 + jp * 2;
          float f0 = W2[(size_t)k0 * TT + tile * 32 + l31];
          float f1 = W2[(size_t)(k0 + 1) * TT + tile * 32 + l31];
          wf.u[jp] = pkbf(f0, f1);
        }
        accl[tile] = __builtin_amdgcn_mfma_f32_32x32x16_bf16(
            ahf[s], wf.v, accl[tile], 0, 0, 0);
      }
      float bt = b2[tile * 32 + l31];
#pragma unroll
      for (int i = 0; i < 16; ++i) accl[tile][i] += bt;
    }

    float mrow[16];
#pragma unroll
    for (int r = 0; r < 16; ++r)
      mrow[r] = fmaxf(fmaxf(accl[0][r], accl[1][r]),
                      fmaxf(accl[2][r], accl[3][r]));
#pragma unroll
    for (int msk = 1; msk <= 16; msk <<= 1)
#pragma unroll
      for (int r = 0; r < 16; ++r)
        mrow[r] = fmaxf(mrow[r], __shfl_xor(mrow[r], msk, 64));
    float srow[16];
#pragma unroll
    for (int r = 0; r < 16; ++r) srow[r] = 0.f;
#pragma unroll
    for (int tile = 0; tile < 4; ++tile)
#pragma unroll
      for (int r = 0; r < 16; ++r) {
        float e = __expf(accl[tile][r] - mrow[r]);
        accl[tile][r] = e;
        srow[r] += e;
      }
#pragma unroll
    for (int msk = 1; msk <= 16; msk <<= 1)
#pragma unroll
      for (int r = 0; r < 16; ++r)
        srow[r] += __shfl_xor(srow[r], msk, 64);
#pragma unroll
    for (int r = 0; r < 16; ++r) srow[r] = 1.f / srow[r];

#pragma unroll
    for (int tile = 0; tile < 4; ++tile)
#pragma unroll
      for (int r = 0; r < 16; ++r) {
        int row = (r & 3) + 8 * (r >> 2) + 4 * half;
        attnB[(size_t)(b0 + row) * TT + tile * 32 + l31] =
            __float2half(accl[tile][r] * srow[r]);
      }

  } else if (blk < 1088) {
    // ------- zs branch (MFMA) -> sPack via LDS transpose, coalesced ---------
    __half* lds = (__half*)smem_raw;       // [tree_local][b_local][8] = 16 KB
    const int blk2 = blk - 64;
    const int mb = blk2 >> 5;              // 0..31
    const int ns = blk2 & 31;              // 0..31, 256 b each
    const int m0 = mb * 28;

    int mr = m0 + l31; if (mr > 895) mr = 895;
    const float* mrow = mask + (size_t)mr * II + half * 8;
    short8 af[8];
#pragma unroll
    for (int s = 0; s < 8; ++s)
      af[s] = cvt8(*(const float4*)(mrow + s * 16),
                   *(const float4*)(mrow + s * 16 + 4));
    float th[16];
#pragma unroll
    for (int r = 0; r < 16; ++r) {
      int m = m0 + (r & 3) + 8 * (r >> 2) + 4 * half;
      th[r] = thr[m > 895 ? 895 : m];
    }

#pragma unroll
    for (int nb = 0; nb < 2; ++nb) {
      const int nl = wv * 64 + nb * 32;
      const float* xrow = x + (size_t)(ns * 256 + nl + l31) * II + half * 8;
      floatx16 acc;
#pragma unroll
      for (int i = 0; i < 16; ++i) acc[i] = 0.f;
#pragma unroll
      for (int s = 0; s < 8; ++s) {
        short8 bf = cvt8(*(const float4*)(xrow + s * 16),
                         *(const float4*)(xrow + s * 16 + 4));
        acc = __builtin_amdgcn_mfma_f32_32x32x16_bf16(af[s], bf, acc, 0, 0, 0);
      }
#pragma unroll
      for (int r = 0; r < 16; ++r) {
        int row = (r & 3) + 8 * (r >> 2) + 4 * half;   // 0..31
        if (row < 28) {
          int tl = row / 7;
          int d = row - tl * 7;
          float z = acc[r] - th[r];
          float o = 0.5f * (z / (1.f + fabsf(z)) + 1.f);
          lds[(tl * 256 + nl + l31) * 8 + d] = __float2half(o);
        }
      }
    }
    __syncthreads();

    const uint4* l4 = (const uint4*)lds;
#pragma unroll
    for (int j = 0; j < 4; ++j) {
      int idx = tid + 256 * j;
      ((uint4*)sPack)[(size_t)(4 * mb + (idx >> 8)) * BB + ns * 256 + (idx & 255)] =
          l4[idx];
    }

  } else {
    // ---------------- prep branch: leaf softmax -> fp16 B-frags -------------
    float* lps = (float*)smem_raw;
    const int t0 = (blk - 1088) * 2;
    {
      int tl = tid >> 7, l = tid & 127;
      const float* row = lo + ((size_t)(t0 + tl) * 128 + l) * CC;
      float v[CC];
      float m = -1e30f;
#pragma unroll
      for (int c = 0; c < CC; ++c) { v[c] = row[c]; m = fmaxf(m, v[c]); }
      float s = 0.f;
#pragma unroll
      for (int c = 0; c < CC; ++c) { v[c] = __expf(v[c] - m); s += v[c]; }
      float inv = 1.f / s;
      float* o = lps + (tl * 128 + l) * 12;
#pragma unroll
      for (int c = 0; c < CC; ++c) o[c] = v[c] * inv;
      o[10] = 0.f; o[11] = 0.f;
    }
    __syncthreads();

#pragma unroll
    for (int jj = 0; jj < 4; ++jj) {
      int idx = tid + 256 * jj;
      int tl = idx >> 9, rem = idx & 511;
      int s = rem >> 6, ln = rem & 63;
      int hf = ln >> 5, n = ln & 31;
      unsigned int wd[4];
#pragma unroll
      for (int jp = 0; jp < 4; ++jp) {
        int l0 = s * 16 + hf * 8 + jp * 2;
        float f0 = (n < CC) ? lps[(tl * 128 + l0) * 12 + n] : 0.f;
        float f1 = (n < CC) ? lps[(tl * 128 + l0 + 1) * 12 + n] : 0.f;
        wd[jp] = pkh(f0, f1);
      }
      ((uint4*)lpb)[(size_t)(t0 + tl) * 512 + s * 64 + ln] =
          make_uint4(wd[0], wd[1], wd[2], wd[3]);
    }
  }
}

// ---------------- Kernel 2: main contraction via MFMA (fp16) ----------------
// grid (32 bg of 256 b, 16 tg of 8 trees); block 256 = 4 waves.
// Wave handles TWO 32-row b-tiles (q=0,1) sharing one bf[8] set per tree ->
// LPb L2 re-read traffic halves (256->128 MB), which was main's bound (R14).
// (256,2): 512 blocks = 2 blocks/CU max anyway; full reg budget, no spill.
__global__ __launch_bounds__(256, 2) void main_kernel(
    const __half* __restrict__ sPack, const __half* __restrict__ attnB,
    const unsigned int* __restrict__ lpb, float* __restrict__ partial) {
  __shared__ float red[256 * 10];
  const int bg = blockIdx.x, tg = blockIdx.y;
  const int tid = threadIdx.x;
  const int w = tid >> 6, lane = tid & 63;
  const int half = lane >> 5;
  const int l31 = lane & 31;
  const int b0 = bg * 256 + w * 64 + l31;      // tile q=0
  const int b1 = b0 + 32;                      // tile q=1
  const uint4* spk = (const uint4*)sPack;

  __half av0[8], av1[8];
  *(uint4*)av0 = *(const uint4*)(attnB + (size_t)b0 * TT + tg * 8);
  *(uint4*)av1 = *(const uint4*)(attnB + (size_t)b1 * TT + tg * 8);

  floatx16 acc0, acc1;
#pragma unroll
  for (int i = 0; i < 16; ++i) { acc0[i] = 0.f; acc1[i] = 0.f; }

  uint4 sv0[2], sv1[2];
  sv0[0] = spk[(size_t)(tg * 8) * BB + b0];
  sv1[0] = spk[(size_t)(tg * 8) * BB + b1];

#pragma unroll
  for (int it = 0; it < 8; ++it) {
    const int cur = it & 1;
    const int t = tg * 8 + it;
    uint4 bf[8];
    const uint4* lpt = (const uint4*)lpb + (size_t)t * 512 + lane;
#pragma unroll
    for (int s = 0; s < 8; ++s) bf[s] = lpt[s * 64];
    if (it < 7) {
      sv0[cur ^ 1] = spk[(size_t)(t + 1) * BB + b0];
      sv1[cur ^ 1] = spk[(size_t)(t + 1) * BB + b1];
    }

    __half2 pl2q[2][4];
    float wvq[2][8];
#pragma unroll
    for (int q = 0; q < 2; ++q) {
      const __half* sh = (const __half*)(q ? &sv1[cur] : &sv0[cur]);
      float s0 = __half2float(sh[0]), s1 = __half2float(sh[1]);
      float s2 = __half2float(sh[2]), s3 = __half2float(sh[3]);
      float s4 = __half2float(sh[4]), s5 = __half2float(sh[5]);
      float s6 = __half2float(sh[6]);
      float A  = __half2float(q ? av1[it] : av0[it]);

      float s0c = 1.f - s0, s1c = 1.f - s1, s2c = 1.f - s2;
      float t0 = s0 * s1, t1 = s0c * s1, t2 = s0 * s1c, t3 = s0c * s1c;
      float pl[8];
      pl[0] = t0 * s2;  pl[1] = t1 * s2;  pl[2] = t2 * s2;  pl[3] = t3 * s2;
      pl[4] = t0 * s2c; pl[5] = t1 * s2c; pl[6] = t2 * s2c; pl[7] = t3 * s2c;
      float sel3 = half ? (1.f - s3) : s3;
      float Af = A * sel3;
      float s4c = 1.f - s4, s5c = 1.f - s5;
      float as6 = Af * s6, as6c = Af * (1.f - s6);
      float u0 = s4 * s5, u1 = s4c * s5, u2 = s4 * s5c, u3 = s4c * s5c;
      wvq[q][0] = u0 * as6;  wvq[q][1] = u1 * as6;
      wvq[q][2] = u2 * as6;  wvq[q][3] = u3 * as6;
      wvq[q][4] = u0 * as6c; wvq[q][5] = u1 * as6c;
      wvq[q][6] = u2 * as6c; wvq[q][7] = u3 * as6c;
#pragma unroll
      for (int jp = 0; jp < 4; ++jp)
        pl2q[q][jp] = __float22half2_rn(make_float2(pl[jp * 2], pl[jp * 2 + 1]));
    }

#pragma unroll
    for (int s = 0; s < 8; ++s) {
      union { short8 v; __half2 h[4]; } a0, a1;
      __half2 w20 = __half2half2(__float2half(wvq[0][s]));
      __half2 w21 = __half2half2(__float2half(wvq[1][s]));
#pragma unroll
      for (int jp = 0; jp < 4; ++jp) {
        a0.h[jp] = __hmul2(pl2q[0][jp], w20);
        a1.h[jp] = __hmul2(pl2q[1][jp], w21);
      }
      acc0 = __builtin_amdgcn_mfma_f32_32x32x16_f16(
          a0.v, *(const short8*)&bf[s], acc0, 0, 0, 0);
      acc1 = __builtin_amdgcn_mfma_f32_32x32x16_f16(
          a1.v, *(const short8*)&bf[s], acc1, 0, 0, 0);
    }
  }

  const int col = l31;
  if (col < CC) {
#pragma unroll
    for (int r = 0; r < 16; ++r) {
      int row = (r & 3) + 8 * (r >> 2) + 4 * half;
      red[(w * 64 + row) * 10 + col] = acc0[r];
      red[(w * 64 + 32 + row) * 10 + col] = acc1[r];
    }
  }
  __syncthreads();
#pragma unroll
  for (int j = 0; j < 10; ++j) {
    int idx = tid + 256 * j;   // 0..2559
    partial[(size_t)tg * 81920 + (size_t)bg * 2560 + idx] = red[idx];
  }
}

// ---------------- Kernel 3: final reduce over 16 tree-groups ----------------
__global__ __launch_bounds__(256) void reduce_kernel(
    const float* __restrict__ partial, float* __restrict__ out) {
  int idx4 = blockIdx.x * 256 + threadIdx.x;  // 0..20479 float4s
  float4 s = make_float4(0.f, 0.f, 0.f, 0.f);
#pragma unroll
  for (int tg = 0; tg < 16; ++tg) {
    float4 v = ((const float4*)(partial + (size_t)tg * 81920))[idx4];
    s.x += v.x; s.y += v.y; s.z += v.z; s.w += v.w;
  }
  ((float4*)out)[idx4] = s;
}

// ---------------------------------------------------------------------------
extern "C" void kernel_launch(void* const* d_in, const int* in_sizes, int n_in,
                              void* d_out, int out_size, void* d_ws, size_t ws_size,
                              hipStream_t stream) {
  const float* x    = (const float*)d_in[0];
  const float* mask = (const float*)d_in[1];
  const float* thr  = (const float*)d_in[2];
  const float* lo   = (const float*)d_in[3];
  const float* W1   = (const float*)d_in[4];
  const float* b1   = (const float*)d_in[5];
  const float* W2   = (const float*)d_in[6];
  const float* b2   = (const float*)d_in[7];
  float* out = (float*)d_out;
  float* ws  = (float*)d_ws;

  __half*       sPack   = (__half*)(ws + OFF_SP);
  __half*       attnB   = (__half*)(ws + OFF_AT);
  unsigned int* LPb     = (unsigned int*)(ws + OFF_LPB);
  float*        partial = ws + OFF_PT;

  phase1_kernel<<<1152, 256, 0, stream>>>(x, mask, thr, lo, W1, b1, W2, b2,
                                          sPack, attnB, LPb);
  main_kernel<<<dim3(32, 16), 256, 0, stream>>>(sPack, attnB, LPb, partial);
  reduce_kernel<<<80, 256, 0, stream>>>(partial, out);
}

// Round 15
// 105.173 us; speedup vs baseline: 1.1840x; 1.0513x over previous
//
#include <hip/hip_runtime.h>
#include <hip/hip_bf16.h>
#include <hip/hip_fp16.h>

// Problem: B=8192, T=128, D=7, I=128, C=10, H=64, L=128
// ws layout (float slots):
//   sPack fp16 [128][8192][8]  off 0          (4,194,304)  d0..6 = s, d7 = junk
//   attnB fp16 [8192][128]     off 4,194,304  (524,288)
//   LPb   fp16 B-frags         off 4,718,592  (262,144)
//   partial [16][8192][10]     off 4,980,736  (1,310,720)
// total 6,291,456 floats = 25.2 MB

#define BB 8192
#define TT 128
#define II 128
#define CC 10
#define HH 64

#define OFF_SP  0
#define OFF_AT  4194304
#define OFF_LPB 4718592
#define OFF_PT  4980736

typedef __attribute__((ext_vector_type(8))) short short8;
typedef __attribute__((ext_vector_type(16))) float floatx16;

static __device__ inline unsigned int pkbf(float lo, float hi) {
  __hip_bfloat162 h = __float22bfloat162_rn(make_float2(lo, hi));
  unsigned int u;
  __builtin_memcpy(&u, &h, 4);
  return u;
}

static __device__ inline unsigned int pkh(float lo, float hi) {
  __half2 h = __float22half2_rn(make_float2(lo, hi));
  unsigned int u;
  __builtin_memcpy(&u, &h, 4);
  return u;
}

static __device__ inline short8 cvt8(float4 a, float4 b) {
  union { short8 v; unsigned int u[4]; } r;
  r.u[0] = pkbf(a.x, a.y);
  r.u[1] = pkbf(a.z, a.w);
  r.u[2] = pkbf(b.x, b.y);
  r.u[3] = pkbf(b.z, b.w);
  return r.v;
}

// ---------------- Phase 1: fused attn (MFMA) + zs (MFMA) + prep -------------
// blocks [0,64): attn | [64,576): zs | [576,640): prep
// Fusion: attn overlaps with zs (R11 split serialized them, +6us).
// zs: each block now covers TWO 28-row m-tiles (8 trees, 56 rows; 16x56=896
// exact) sharing one x-fragment set per nb -> x L2 re-read halves 128->64 MB
// (R14's main fix applied to zs). sPack written directly via 32KB-LDS
// transpose (R13). (256,2): attn/zs branches hold ~180-200 unified regs
// (R7: (256,4) spilled, +18us). All global stores coalesced (R9).
__global__ __launch_bounds__(256, 2) void phase1_kernel(
    const float* __restrict__ x, const float* __restrict__ mask,
    const float* __restrict__ thr, const float* __restrict__ lo,
    const float* __restrict__ W1, const float* __restrict__ b1,
    const float* __restrict__ W2, const float* __restrict__ b2,
    __half* __restrict__ sPack, __half* __restrict__ attnB,
    unsigned int* __restrict__ lpb) {
  __shared__ __align__(16) char smem_raw[32768];   // 32 KB
  const int blk = blockIdx.x;
  const int tid = threadIdx.x;
  const int wv = tid >> 6, lane = tid & 63;
  const int half = lane >> 5, l31 = lane & 31;

  if (blk < 64) {
    // ---------------- attn branch: 128 b-rows/block, 32/wave ----------------
    const int b0 = blk * 128 + wv * 32;

    short8 axf[8];
    const float* xrow = x + (size_t)(b0 + l31) * II + half * 8;
#pragma unroll
    for (int s = 0; s < 8; ++s)
      axf[s] = cvt8(*(const float4*)(xrow + s * 16),
                    *(const float4*)(xrow + s * 16 + 4));

    floatx16 acch[2];
#pragma unroll
    for (int i = 0; i < 16; ++i) { acch[0][i] = 0.f; acch[1][i] = 0.f; }
#pragma unroll
    for (int s = 0; s < 8; ++s) {
#pragma unroll
      for (int tile = 0; tile < 2; ++tile) {
        union { short8 v; unsigned int u[4]; } wf;
#pragma unroll
        for (int jp = 0; jp < 4; ++jp) {
          int k0 = s * 16 + half * 8 + jp * 2;
          float f0 = W1[(size_t)k0 * HH + tile * 32 + l31];
          float f1 = W1[(size_t)(k0 + 1) * HH + tile * 32 + l31];
          wf.u[jp] = pkbf(f0, f1);
        }
        acch[tile] = __builtin_amdgcn_mfma_f32_32x32x16_bf16(
            axf[s], wf.v, acch[tile], 0, 0, 0);
      }
    }
    __hip_bfloat16* hids = (__hip_bfloat16*)smem_raw + wv * (32 * 72);
#pragma unroll
    for (int tile = 0; tile < 2; ++tile) {
      float bh = b1[tile * 32 + l31];
#pragma unroll
      for (int r = 0; r < 16; ++r) {
        int row = (r & 3) + 8 * (r >> 2) + 4 * half;
        hids[row * 72 + tile * 32 + l31] =
            __float2bfloat16(fmaxf(acch[tile][r] + bh, 0.f));
      }
    }
    __syncthreads();

    short8 ahf[4];
#pragma unroll
    for (int s = 0; s < 4; ++s)
      ahf[s] = *(const short8*)(hids + l31 * 72 + s * 16 + half * 8);

    floatx16 accl[4];
#pragma unroll
    for (int tile = 0; tile < 4; ++tile) {
#pragma unroll
      for (int i = 0; i < 16; ++i) accl[tile][i] = 0.f;
#pragma unroll
      for (int s = 0; s < 4; ++s) {
        union { short8 v; unsigned int u[4]; } wf;
#pragma unroll
        for (int jp = 0; jp < 4; ++jp) {
          int k0 = s * 16 + half * 8 + jp * 2;
          float f0 = W2[(size_t)k0 * TT + tile * 32 + l31];
          float f1 = W2[(size_t)(k0 + 1) * TT + tile * 32 + l31];
          wf.u[jp] = pkbf(f0, f1);
        }
        accl[tile] = __builtin_amdgcn_mfma_f32_32x32x16_bf16(
            ahf[s], wf.v, accl[tile], 0, 0, 0);
      }
      float bt = b2[tile * 32 + l31];
#pragma unroll
      for (int i = 0; i < 16; ++i) accl[tile][i] += bt;
    }

    float mrow[16];
#pragma unroll
    for (int r = 0; r < 16; ++r)
      mrow[r] = fmaxf(fmaxf(accl[0][r], accl[1][r]),
                      fmaxf(accl[2][r], accl[3][r]));
#pragma unroll
    for (int msk = 1; msk <= 16; msk <<= 1)
#pragma unroll
      for (int r = 0; r < 16; ++r)
        mrow[r] = fmaxf(mrow[r], __shfl_xor(mrow[r], msk, 64));
    float srow[16];
#pragma unroll
    for (int r = 0; r < 16; ++r) srow[r] = 0.f;
#pragma unroll
    for (int tile = 0; tile < 4; ++tile)
#pragma unroll
      for (int r = 0; r < 16; ++r) {
        float e = __expf(accl[tile][r] - mrow[r]);
        accl[tile][r] = e;
        srow[r] += e;
      }
#pragma unroll
    for (int msk = 1; msk <= 16; msk <<= 1)
#pragma unroll
      for (int r = 0; r < 16; ++r)
        srow[r] += __shfl_xor(srow[r], msk, 64);
#pragma unroll
    for (int r = 0; r < 16; ++r) srow[r] = 1.f / srow[r];

#pragma unroll
    for (int tile = 0; tile < 4; ++tile)
#pragma unroll
      for (int r = 0; r < 16; ++r) {
        int row = (r & 3) + 8 * (r >> 2) + 4 * half;
        attnB[(size_t)(b0 + row) * TT + tile * 32 + l31] =
            __float2half(accl[tile][r] * srow[r]);
      }

  } else if (blk < 576) {
    // ------- zs branch (MFMA, 2 m-tiles/block) -> sPack via LDS -------------
    // Tiles: rows m0..m0+27 (trees 8mb..8mb+3) and m0+28..m0+55 (trees
    // 8mb+4..8mb+7), m0 = mb*56. x-fragments loaded ONCE per nb, shared by
    // both A-fragment sets. OOB mask/thr rows (tile B, mb=15) clamped;
    // their results are discarded (row>=28 in tile).
    __half* lds = (__half*)smem_raw;   // [tree_local 0..7][b_local 0..255][8]
    const int blk2 = blk - 64;
    const int mb = blk2 >> 5;          // 0..15
    const int ns = blk2 & 31;          // 0..31, 256 b each
    const int m0 = mb * 56;

    short8 af0[8], af1[8];
    {
      const float* mrow0 = mask + (size_t)(m0 + l31) * II + half * 8;
      int mr1 = m0 + 28 + l31; if (mr1 > 895) mr1 = 895;
      const float* mrow1 = mask + (size_t)mr1 * II + half * 8;
#pragma unroll
      for (int s = 0; s < 8; ++s) {
        af0[s] = cvt8(*(const float4*)(mrow0 + s * 16),
                      *(const float4*)(mrow0 + s * 16 + 4));
        af1[s] = cvt8(*(const float4*)(mrow1 + s * 16),
                      *(const float4*)(mrow1 + s * 16 + 4));
      }
    }
    float th0[16], th1[16];
#pragma unroll
    for (int r = 0; r < 16; ++r) {
      int rw = (r & 3) + 8 * (r >> 2) + 4 * half;
      th0[r] = thr[m0 + rw];
      int m1 = m0 + 28 + rw;
      th1[r] = thr[m1 > 895 ? 895 : m1];
    }

#pragma unroll
    for (int nb = 0; nb < 2; ++nb) {
      const int nl = wv * 64 + nb * 32;
      const float* xrow = x + (size_t)(ns * 256 + nl + l31) * II + half * 8;
      short8 xf[8];
#pragma unroll
      for (int s = 0; s < 8; ++s)
        xf[s] = cvt8(*(const float4*)(xrow + s * 16),
                     *(const float4*)(xrow + s * 16 + 4));
      floatx16 acc0, acc1;
#pragma unroll
      for (int i = 0; i < 16; ++i) { acc0[i] = 0.f; acc1[i] = 0.f; }
#pragma unroll
      for (int s = 0; s < 8; ++s) {
        acc0 = __builtin_amdgcn_mfma_f32_32x32x16_bf16(af0[s], xf[s], acc0, 0, 0, 0);
        acc1 = __builtin_amdgcn_mfma_f32_32x32x16_bf16(af1[s], xf[s], acc1, 0, 0, 0);
      }
#pragma unroll
      for (int r = 0; r < 16; ++r) {
        int row = (r & 3) + 8 * (r >> 2) + 4 * half;   // 0..31
        if (row < 28) {
          int tl = row / 7;
          int d = row - tl * 7;
          float z = acc0[r] - th0[r];
          float o = 0.5f * (z / (1.f + fabsf(z)) + 1.f);
          lds[(tl * 256 + nl + l31) * 8 + d] = __float2half(o);
          z = acc1[r] - th1[r];
          o = 0.5f * (z / (1.f + fabsf(z)) + 1.f);
          lds[((tl + 4) * 256 + nl + l31) * 8 + d] = __float2half(o);
        }
      }
    }
    __syncthreads();

    // coalesced store: 8 uint4/thread; slot 7 junk (never read by main)
    const uint4* l4 = (const uint4*)lds;
#pragma unroll
    for (int j = 0; j < 8; ++j) {
      int idx = tid + 256 * j;             // 0..2047: tree = idx>>8, bl = idx&255
      ((uint4*)sPack)[(size_t)(8 * mb + (idx >> 8)) * BB + ns * 256 + (idx & 255)] =
          l4[idx];
    }

  } else {
    // ---------------- prep branch: leaf softmax -> fp16 B-frags -------------
    float* lps = (float*)smem_raw;
    const int t0 = (blk - 576) * 2;
    {
      int tl = tid >> 7, l = tid & 127;
      const float* row = lo + ((size_t)(t0 + tl) * 128 + l) * CC;
      float v[CC];
      float m = -1e30f;
#pragma unroll
      for (int c = 0; c < CC; ++c) { v[c] = row[c]; m = fmaxf(m, v[c]); }
      float s = 0.f;
#pragma unroll
      for (int c = 0; c < CC; ++c) { v[c] = __expf(v[c] - m); s += v[c]; }
      float inv = 1.f / s;
      float* o = lps + (tl * 128 + l) * 12;
#pragma unroll
      for (int c = 0; c < CC; ++c) o[c] = v[c] * inv;
      o[10] = 0.f; o[11] = 0.f;
    }
    __syncthreads();

#pragma unroll
    for (int jj = 0; jj < 4; ++jj) {
      int idx = tid + 256 * jj;
      int tl = idx >> 9, rem = idx & 511;
      int s = rem >> 6, ln = rem & 63;
      int hf = ln >> 5, n = ln & 31;
      unsigned int wd[4];
#pragma unroll
      for (int jp = 0; jp < 4; ++jp) {
        int l0 = s * 16 + hf * 8 + jp * 2;
        float f0 = (n < CC) ? lps[(tl * 128 + l0) * 12 + n] : 0.f;
        float f1 = (n < CC) ? lps[(tl * 128 + l0 + 1) * 12 + n] : 0.f;
        wd[jp] = pkh(f0, f1);
      }
      ((uint4*)lpb)[(size_t)(t0 + tl) * 512 + s * 64 + ln] =
          make_uint4(wd[0], wd[1], wd[2], wd[3]);
    }
  }
}

// ---------------- Kernel 2: main contraction via MFMA (fp16) ----------------
// grid (32 bg of 256 b, 16 tg of 8 trees); block 256 = 4 waves.
// Wave handles TWO 32-row b-tiles sharing one bf[8] set per tree (R14:
// halved LPb L2 traffic, main's bound). (256,2), no spill.
__global__ __launch_bounds__(256, 2) void main_kernel(
    const __half* __restrict__ sPack, const __half* __restrict__ attnB,
    const unsigned int* __restrict__ lpb, float* __restrict__ partial) {
  __shared__ float red[256 * 10];
  const int bg = blockIdx.x, tg = blockIdx.y;
  const int tid = threadIdx.x;
  const int w = tid >> 6, lane = tid & 63;
  const int half = lane >> 5;
  const int l31 = lane & 31;
  const int b0 = bg * 256 + w * 64 + l31;
  const int b1 = b0 + 32;
  const uint4* spk = (const uint4*)sPack;

  __half av0[8], av1[8];
  *(uint4*)av0 = *(const uint4*)(attnB + (size_t)b0 * TT + tg * 8);
  *(uint4*)av1 = *(const uint4*)(attnB + (size_t)b1 * TT + tg * 8);

  floatx16 acc0, acc1;
#pragma unroll
  for (int i = 0; i < 16; ++i) { acc0[i] = 0.f; acc1[i] = 0.f; }

  uint4 sv0[2], sv1[2];
  sv0[0] = spk[(size_t)(tg * 8) * BB + b0];
  sv1[0] = spk[(size_t)(tg * 8) * BB + b1];

#pragma unroll
  for (int it = 0; it < 8; ++it) {
    const int cur = it & 1;
    const int t = tg * 8 + it;
    uint4 bf[8];
    const uint4* lpt = (const uint4*)lpb + (size_t)t * 512 + lane;
#pragma unroll
    for (int s = 0; s < 8; ++s) bf[s] = lpt[s * 64];
    if (it < 7) {
      sv0[cur ^ 1] = spk[(size_t)(t + 1) * BB + b0];
      sv1[cur ^ 1] = spk[(size_t)(t + 1) * BB + b1];
    }

    __half2 pl2q[2][4];
    float wvq[2][8];
#pragma unroll
    for (int q = 0; q < 2; ++q) {
      const __half* sh = (const __half*)(q ? &sv1[cur] : &sv0[cur]);
      float s0 = __half2float(sh[0]), s1 = __half2float(sh[1]);
      float s2 = __half2float(sh[2]), s3 = __half2float(sh[3]);
      float s4 = __half2float(sh[4]), s5 = __half2float(sh[5]);
      float s6 = __half2float(sh[6]);
      float A  = __half2float(q ? av1[it] : av0[it]);

      float s0c = 1.f - s0, s1c = 1.f - s1, s2c = 1.f - s2;
      float t0 = s0 * s1, t1 = s0c * s1, t2 = s0 * s1c, t3 = s0c * s1c;
      float pl[8];
      pl[0] = t0 * s2;  pl[1] = t1 * s2;  pl[2] = t2 * s2;  pl[3] = t3 * s2;
      pl[4] = t0 * s2c; pl[5] = t1 * s2c; pl[6] = t2 * s2c; pl[7] = t3 * s2c;
      float sel3 = half ? (1.f - s3) : s3;
      float Af = A * sel3;
      float s4c = 1.f - s4, s5c = 1.f - s5;
      float as6 = Af * s6, as6c = Af * (1.f - s6);
      float u0 = s4 * s5, u1 = s4c * s5, u2 = s4 * s5c, u3 = s4c * s5c;
      wvq[q][0] = u0 * as6;  wvq[q][1] = u1 * as6;
      wvq[q][2] = u2 * as6;  wvq[q][3] = u3 * as6;
      wvq[q][4] = u0 * as6c; wvq[q][5] = u1 * as6c;
      wvq[q][6] = u2 * as6c; wvq[q][7] = u3 * as6c;
#pragma unroll
      for (int jp = 0; jp < 4; ++jp)
        pl2q[q][jp] = __float22half2_rn(make_float2(pl[jp * 2], pl[jp * 2 + 1]));
    }

#pragma unroll
    for (int s = 0; s < 8; ++s) {
      union { short8 v; __half2 h[4]; } a0, a1;
      __half2 w20 = __half2half2(__float2half(wvq[0][s]));
      __half2 w21 = __half2half2(__float2half(wvq[1][s]));
#pragma unroll
      for (int jp = 0; jp < 4; ++jp) {
        a0.h[jp] = __hmul2(pl2q[0][jp], w20);
        a1.h[jp] = __hmul2(pl2q[1][jp], w21);
      }
      acc0 = __builtin_amdgcn_mfma_f32_32x32x16_f16(
          a0.v, *(const short8*)&bf[s], acc0, 0, 0, 0);
      acc1 = __builtin_amdgcn_mfma_f32_32x32x16_f16(
          a1.v, *(const short8*)&bf[s], acc1, 0, 0, 0);
    }
  }

  const int col = l31;
  if (col < CC) {
#pragma unroll
    for (int r = 0; r < 16; ++r) {
      int row = (r & 3) + 8 * (r >> 2) + 4 * half;
      red[(w * 64 + row) * 10 + col] = acc0[r];
      red[(w * 64 + 32 + row) * 10 + col] = acc1[r];
    }
  }
  __syncthreads();
#pragma unroll
  for (int j = 0; j < 10; ++j) {
    int idx = tid + 256 * j;   // 0..2559
    partial[(size_t)tg * 81920 + (size_t)bg * 2560 + idx] = red[idx];
  }
}

// ---------------- Kernel 3: final reduce over 16 tree-groups ----------------
__global__ __launch_bounds__(256) void reduce_kernel(
    const float* __restrict__ partial, float* __restrict__ out) {
  int idx4 = blockIdx.x * 256 + threadIdx.x;  // 0..20479 float4s
  float4 s = make_float4(0.f, 0.f, 0.f, 0.f);
#pragma unroll
  for (int tg = 0; tg < 16; ++tg) {
    float4 v = ((const float4*)(partial + (size_t)tg * 81920))[idx4];
    s.x += v.x; s.y += v.y; s.z += v.z; s.w += v.w;
  }
  ((float4*)out)[idx4] = s;
}

// ---------------------------------------------------------------------------
extern "C" void kernel_launch(void* const* d_in, const int* in_sizes, int n_in,
                              void* d_out, int out_size, void* d_ws, size_t ws_size,
                              hipStream_t stream) {
  const float* x    = (const float*)d_in[0];
  const float* mask = (const float*)d_in[1];
  const float* thr  = (const float*)d_in[2];
  const float* lo   = (const float*)d_in[3];
  const float* W1   = (const float*)d_in[4];
  const float* b1   = (const float*)d_in[5];
  const float* W2   = (const float*)d_in[6];
  const float* b2   = (const float*)d_in[7];
  float* out = (float*)d_out;
  float* ws  = (float*)d_ws;

  __half*       sPack   = (__half*)(ws + OFF_SP);
  __half*       attnB   = (__half*)(ws + OFF_AT);
  unsigned int* LPb     = (unsigned int*)(ws + OFF_LPB);
  float*        partial = ws + OFF_PT;

  phase1_kernel<<<640, 256, 0, stream>>>(x, mask, thr, lo, W1, b1, W2, b2,
                                         sPack, attnB, LPb);
  main_kernel<<<dim3(32, 16), 256, 0, stream>>>(sPack, attnB, LPb, partial);
  reduce_kernel<<<80, 256, 0, stream>>>(partial, out);
}